// Round 10
// baseline (443.828 us; speedup 1.0000x reference)
//
#include <hip/hip_runtime.h>

#define BB 1024
#define TT 512
#define KK 64
#define NEGV -10000.0f

typedef _Float16 h2 __attribute__((ext_vector_type(2)));

#if defined(__has_builtin)
#if __has_builtin(__builtin_amdgcn_fdot2)
#define HAVE_FDOT2 1
#endif
#endif

static __device__ __forceinline__ float dot2_acc(h2 a, h2 b, float c) {
#ifdef HAVE_FDOT2
    return __builtin_amdgcn_fdot2(a, b, c, false);
#else
    return fmaf((float)a.x, (float)b.x, fmaf((float)a.y, (float)b.y, c));
#endif
}

static __device__ __forceinline__ h2 bc_h2(float f) {
    return __builtin_bit_cast(h2, f);
}

// quad_perm DPP exchanges (pure VALU v_mov_b32_dpp; involutions, so
// direction-proof): ^1 = [1,0,3,2] = 0xB1, ^2 = [2,3,0,1] = 0x4E
#define QP_X1 0xB1
#define QP_X2 0x4E
template <int CTRL>
static __device__ __forceinline__ float dppf(float x) {
    return __builtin_bit_cast(
        float, __builtin_amdgcn_update_dpp(0, __builtin_bit_cast(int, x),
                                           CTRL, 0xF, 0xF, true));
}
template <int CTRL>
static __device__ __forceinline__ int dppi(int x) {
    return __builtin_amdgcn_update_dpp(0, x, CTRL, 0xF, 0xF, true);
}

// ---------------------------------------------------------------------------
// crf_kernel: ONE BLOCK (4 waves) PER BATCH -- cooperative state-split.
// Wave wv owns states [16wv, 16wv+16); lane = (state n = 16wv + (l>>2),
// prev-quarter q = l&3, prevs p in [16q, 16q+16)).
//   V: 16 exact fp32 adds + max3 tree per lane; cross-quarter max via 2
//      quad_perm DPP (VALU, no DS); global-max equality scan (descending ->
//      smallest j) + cross-quarter min-index => exact first-index argmax.
//   F: 8 dot2 partial per lane + 2 DPP-add butterflies (commutative sums,
//      all 4 dup lanes bitwise equal); ref normalizer via 4-slot LDS ring
//      written 2 steps ahead (R6 staleness + e^11 clamp).
// Publish w/ea through double-buffered LDS; ONE __syncthreads per step.
// Occupancy: 4096 waves total -> 4 waves/SIMD (vs 1 for all prior rounds).
// ---------------------------------------------------------------------------
__global__ __launch_bounds__(256, 1) void crf_kernel(const float* __restrict__ feats,
                                                     const int* __restrict__ tags,
                                                     const float* __restrict__ trans,
                                                     float* __restrict__ out) {
    __shared__ unsigned char bp[TT][KK];              // 32 KB backpointers
    __shared__ __align__(16) float wa_buf[2][KK];     // viterbi alpha, dbuf
    __shared__ __align__(16) _Float16 ea_buf[2][KK];  // exp(alpha-ref) f16, dbuf
    __shared__ float ring[4];                         // ref normalizer ring
    __shared__ float af[KK];                          // final forward alpha

    const int b = blockIdx.x;
    const int tid = threadIdx.x;
    const int wv = tid >> 6;
    const int lane = tid & 63;
    const int n = (wv << 4) + (lane >> 2);   // owned state
    const int q = lane & 3;                  // prev quarter
    const int q16 = q << 4;

    // ---- gold score + terminal row (wave 0 only) ----
    float gold = 0.f;
    float t63v = 0.f;
    if (wv == 0) {
        const int* tg = tags + (size_t)b * TT;
#pragma unroll
        for (int i = 0; i < TT / 64; ++i) {
            int t = lane + i * 64;
            int nxt = tg[t];
            int prv = t ? tg[t - 1] : 0;
            gold += trans[nxt * KK + prv] + feats[((size_t)b * TT + t) * KK + nxt];
        }
        if (lane == 0) gold += trans[(KK - 1) * KK + tg[TT - 1]];
#pragma unroll
        for (int d = 1; d < 64; d <<= 1) gold += __shfl_xor(gold, d);
        t63v = trans[(KK - 1) * KK + lane];  // trans[STOP][lane]
    }

    // ---- per-lane transition quarter: trq[k] = trans[n][16q+k] ----
    float trq[16];
    h2 erq[8];
    {
        const float4* tq = reinterpret_cast<const float4*>(trans + n * KK + q16);
        float4 t0 = tq[0], t1 = tq[1], t2 = tq[2], t3 = tq[3];
        trq[0] = t0.x;  trq[1] = t0.y;  trq[2] = t0.z;  trq[3] = t0.w;
        trq[4] = t1.x;  trq[5] = t1.y;  trq[6] = t1.z;  trq[7] = t1.w;
        trq[8] = t2.x;  trq[9] = t2.y;  trq[10] = t2.z; trq[11] = t2.w;
        trq[12] = t3.x; trq[13] = t3.y; trq[14] = t3.z; trq[15] = t3.w;
#pragma unroll
        for (int k = 0; k < 8; ++k) {
            h2 e;
            e.x = (_Float16)__expf(trq[2 * k]);
            e.y = (_Float16)__expf(trq[2 * k + 1]);
            erq[k] = e;
        }
    }

    // ---- init alpha / viterbi state ----
    if (q == 0) {
        float a0 = (n == 0) ? 0.f : NEGV;
        wa_buf[0][n] = a0;
        ea_buf[0][n] = (_Float16)__expf(fminf(a0, 11.f));   // ref(0) = 0
    }
    if (tid == 0) { ring[2] = 0.f; ring[3] = 6.f; }   // refUse(0)=0, refUse(1)=6
    __syncthreads();

    float a = (n == 0) ? 0.f : NEGV;
    float refCur = 0.f;

    // feats prefetch ring (depth 4); each lane reads its state's emission
    const float* fbp = feats + (size_t)b * TT * KK + n;
    float f0 = fbp[0 * KK];
    float f1 = fbp[1 * KK];
    float f2 = fbp[2 * KK];
    float f3 = fbp[3 * KK];
    const float* fp = fbp + 4 * KK;

    int cur = 0;
    for (int t = 0; t < TT; ++t) {
        const int nx = cur ^ 1;

        // DS reads first (uniform per q-group, broadcast-friendly)
        const float4* wq = reinterpret_cast<const float4*>(&wa_buf[cur][q16]);
        float4 wa0 = wq[0], wa1 = wq[1], wa2 = wq[2], wa3 = wq[3];
        const float4* eq = reinterpret_cast<const float4*>(&ea_buf[cur][q16]);
        float4 eA = eq[0], eB = eq[1];
        const float refNext = ring[(t + 3) & 3];   // = refUse(t+1), 2-step-old

        const float f_cur = f0;
        f0 = f1; f1 = f2; f2 = f3;
        f3 = *fp;                       // row min(t+4, TT-1)
        if (t + 5 < TT) fp += KK;

        // ======== viterbi: 16 exact candidates ========
        float c0 = wa0.x + trq[0],  c1 = wa0.y + trq[1];
        float c2 = wa0.z + trq[2],  c3 = wa0.w + trq[3];
        float c4 = wa1.x + trq[4],  c5 = wa1.y + trq[5];
        float c6 = wa1.z + trq[6],  c7 = wa1.w + trq[7];
        float c8 = wa2.x + trq[8],  c9 = wa2.y + trq[9];
        float c10 = wa2.z + trq[10], c11 = wa2.w + trq[11];
        float c12 = wa3.x + trq[12], c13 = wa3.y + trq[13];
        float c14 = wa3.z + trq[14], c15 = wa3.w + trq[15];

        float x0 = fmaxf(fmaxf(c0, c1), c2);
        float x1 = fmaxf(fmaxf(c3, c4), c5);
        float x2 = fmaxf(fmaxf(c6, c7), c8);
        float x3 = fmaxf(fmaxf(c9, c10), c11);
        float x4 = fmaxf(fmaxf(c12, c13), c14);
        float lm = fmaxf(fmaxf(fmaxf(x0, x1), x2), fmaxf(fmaxf(x3, x4), c15));

        // cross-quarter max (4 dup lanes per state; fmax commutes => exact)
        float m1 = fmaxf(lm, dppf<QP_X1>(lm));
        float m = fmaxf(m1, dppf<QP_X2>(m1));

        // first-index argmax: descending equality scan (smallest j wins), then
        // min over quarters (smallest p wins). m is bit-equal to some c_j.
        int li = 4096;
        if (c15 == m) li = q16 + 15;
        if (c14 == m) li = q16 + 14;
        if (c13 == m) li = q16 + 13;
        if (c12 == m) li = q16 + 12;
        if (c11 == m) li = q16 + 11;
        if (c10 == m) li = q16 + 10;
        if (c9 == m) li = q16 + 9;
        if (c8 == m) li = q16 + 8;
        if (c7 == m) li = q16 + 7;
        if (c6 == m) li = q16 + 6;
        if (c5 == m) li = q16 + 5;
        if (c4 == m) li = q16 + 4;
        if (c3 == m) li = q16 + 3;
        if (c2 == m) li = q16 + 2;
        if (c1 == m) li = q16 + 1;
        if (c0 == m) li = q16 + 0;
        int li1 = min(li, dppi<QP_X1>(li));
        int bpv = min(li1, dppi<QP_X2>(li1));

        const float w_new = m + f_cur;

        // ======== forward: partial dot over this quarter ========
        float sA = 0.f, sB = 0.f;
        sA = dot2_acc(bc_h2(eA.x), erq[0], sA);
        sA = dot2_acc(bc_h2(eA.y), erq[1], sA);
        sA = dot2_acc(bc_h2(eA.z), erq[2], sA);
        sA = dot2_acc(bc_h2(eA.w), erq[3], sA);
        sB = dot2_acc(bc_h2(eB.x), erq[4], sB);
        sB = dot2_acc(bc_h2(eB.y), erq[5], sB);
        sB = dot2_acc(bc_h2(eB.z), erq[6], sB);
        sB = dot2_acc(bc_h2(eB.w), erq[7], sB);
        float sp = sA + sB;
        float s1 = sp + dppf<QP_X1>(sp);       // commutative adds: all 4 dup
        float s = s1 + dppf<QP_X2>(s1);        // lanes bitwise identical
        float a_new = __logf(s) + refCur + f_cur;
        float eaN = __expf(fminf(a_new - refNext, 11.f));   // e^11 < f16 max

        // ======== publish (owner lanes), next-step ref sample ========
        if (q == 0) {
            bp[t][n] = (unsigned char)bpv;
            wa_buf[nx][n] = w_new;
            ea_buf[nx][n] = (_Float16)eaN;
        }
        if (wv == 0 && lane == 8) ring[t & 3] = a_new + 5.f;  // state 2 sample

        a = a_new;
        refCur = refNext;
        cur = nx;
        __syncthreads();
    }

    if (q == 0) af[n] = a;
    __syncthreads();

    if (wv == 0) {
        // ---- forward score: exact logsumexp(alpha_T + trans[STOP][:]) ----
        float v = af[lane] + t63v;
        float mm = v;
#pragma unroll
        for (int d = 32; d; d >>= 1) mm = fmaxf(mm, __shfl_xor(mm, d));
        float es = __expf(v - mm);
#pragma unroll
        for (int d = 32; d; d >>= 1) es += __shfl_xor(es, d);
        float fscore = mm + __logf(es);

        // ---- viterbi terminal: max + first-index argmax (exact) ----
        float tv = wa_buf[cur][lane] + t63v;
        float bvv = tv;
        int bidx = lane;
#pragma unroll
        for (int d = 1; d < 64; d <<= 1) {
            float ov = __shfl_xor(bvv, d);
            int oi = __shfl_xor(bidx, d);
            bool take = (ov > bvv) || (ov == bvv && oi < bidx);
            bvv = take ? ov : bvv;
            bidx = take ? oi : bidx;
        }

        if (lane == 0) {
            out[b] = fscore - gold;
            out[BB + b] = bvv;
        }

        // ---- backtrace: bulk LDS row loads + dynamic-shfl chain ----
        float* outp = out + 2 * BB + (size_t)b * TT;
        int curp = bidx;                // wave-uniform
        float my = 0.f;                 // latched path values (lane = t & 63)
        for (int tb = TT - 16; tb >= 0; tb -= 16) {
            int r[16];
#pragma unroll
            for (int j = 0; j < 16; ++j) r[j] = bp[tb + j][lane];
#pragma unroll
            for (int j = 15; j >= 0; --j) {
                my = (lane == ((tb + j) & 63)) ? (float)curp : my;
                curp = __shfl(r[j], curp);
            }
            if ((tb & 63) == 0) outp[tb + lane] = my;   // coalesced store
        }
    }
}

extern "C" void kernel_launch(void* const* d_in, const int* in_sizes, int n_in,
                              void* d_out, int out_size, void* d_ws, size_t ws_size,
                              hipStream_t stream) {
    const float* feats = (const float*)d_in[0];
    const int* tags = (const int*)d_in[1];
    const float* trans = (const float*)d_in[2];
    float* out = (float*)d_out;

    crf_kernel<<<BB, 256, 0, stream>>>(feats, tags, trans, out);
}